// Round 3
// baseline (390.070 us; speedup 1.0000x reference)
//
#include <hip/hip_runtime.h>

typedef _Float16 f16;
typedef _Float16 half8 __attribute__((ext_vector_type(8)));
typedef _Float16 half4 __attribute__((ext_vector_type(4)));
typedef float f32x4 __attribute__((ext_vector_type(4)));

#define B_SZ 512
#define NQ   128
#define CH   512
#define NH   8
#define DH   64
#define MTOK (B_SZ*NQ)   // 65536 tokens
#define KD   512

#define MFMA16(a,b,c) __builtin_amdgcn_mfma_f32_16x16x32_f16((a),(b),(c),0,0,0)

// global -> LDS direct DMA, 16B per lane. LDS dest is wave-uniform base + lane*16.
#define GLDS16(g,l) __builtin_amdgcn_global_load_lds( \
    (__attribute__((address_space(1))) void*)(g), \
    (__attribute__((address_space(3))) void*)(l), 16, 0, 0)

// ---------------- kernel 0a: x fp32 -> fp16 ----------------
__global__ __launch_bounds__(256) void k_cvt(const float* __restrict__ x,
                                             f16* __restrict__ xb) {
  const int n8 = MTOK * KD / 8;
  int i = blockIdx.x * blockDim.x + threadIdx.x;
  const int stride = gridDim.x * blockDim.x;
  for (; i < n8; i += stride) {
    f32x4 a = ((const f32x4*)x)[2 * i];
    f32x4 b = ((const f32x4*)x)[2 * i + 1];
    half8 h;
    h[0] = (f16)a[0]; h[1] = (f16)a[1]; h[2] = (f16)a[2]; h[3] = (f16)a[3];
    h[4] = (f16)b[0]; h[5] = (f16)b[1]; h[6] = (f16)b[2]; h[7] = (f16)b[3];
    ((half8*)xb)[i] = h;
  }
}

// ---------------- kernel 0b: W^T fp32 -> fp16 (B^T layout) ----------------
// wt rows 0..511 = Wq cols, 512..1023 = Wk cols, 1024..1535 = Wv cols, 1536..2047 = Wo cols
__global__ __launch_bounds__(256) void k_wt(const float* __restrict__ Wq,
                                            const float* __restrict__ Wk,
                                            const float* __restrict__ Wv,
                                            const float* __restrict__ Wo,
                                            f16* __restrict__ wt) {
  const int n = blockIdx.x;
  const float* W = (n < 512) ? Wq : (n < 1024) ? Wk : (n < 1536) ? Wv : Wo;
  const int c = n & 511;
  for (int k = threadIdx.x; k < 512; k += blockDim.x)
    wt[n * 512 + k] = (f16)W[k * 512 + c];
}

// ================= 256x256 8-phase GEMM mainloop (BK=64, K=512) =================
template<bool SW, int MB>
__device__ __forceinline__ void mfma16x(f32x4 (&acc)[8][4], half8 (&af)[4], half8 (&bf)[4]) {
#pragma unroll
  for (int i = 0; i < 4; ++i)
#pragma unroll
    for (int n = 0; n < 4; ++n) {
      if (SW) acc[MB + i][n] = MFMA16(bf[n], af[i], acc[MB + i][n]);
      else    acc[MB + i][n] = MFMA16(af[i], bf[n], acc[MB + i][n]);
    }
}

__device__ __forceinline__ void load4(const f16* base, half8 (&fr)[4]) {
#pragma unroll
  for (int n = 0; n < 4; ++n) fr[n] = *(const half8*)(base + n * 512);
}

#define BAR_MFMA_OPEN() __builtin_amdgcn_s_barrier(); \
  asm volatile("s_waitcnt lgkmcnt(0)" ::: "memory"); \
  __builtin_amdgcn_sched_barrier(0); \
  __builtin_amdgcn_s_setprio(1)
#define MFMA_CLOSE() __builtin_amdgcn_s_setprio(0); __builtin_amdgcn_s_barrier()
#define MFMA_CLOSE_GATE4() __builtin_amdgcn_s_setprio(0); \
  asm volatile("s_waitcnt vmcnt(4)" ::: "memory"); \
  __builtin_amdgcn_s_barrier()
#define MFMA_CLOSE_GATE0() __builtin_amdgcn_s_setprio(0); \
  asm volatile("s_waitcnt vmcnt(0)" ::: "memory"); \
  __builtin_amdgcn_s_barrier()

template<bool SW>
__device__ __forceinline__ void gemm256_main(
    const f16* __restrict__ Ag, const f16* __restrict__ Bg,
    int arow0, f16* lds, f32x4 (&acc)[8][4]) {
  const int tid = threadIdx.x;
  const int w = tid >> 6, lane = tid & 63;
  const int ln = lane & 15, g = lane >> 4;
  const int wm = w >> 2, wn = w & 3;
  const int slotx = ((g ^ ((ln >> 1) & 3)) << 3);

  f16* la = lds;           // [2][2][256][32]
  f16* lb = lds + 32768;

  const int gsrc = (((tid & 3) ^ ((tid >> 3) & 3)) << 3);
  int soA[4], soB[4];
#pragma unroll
  for (int ks2 = 0; ks2 < 2; ++ks2)
#pragma unroll
    for (int r = 0; r < 2; ++r) {
      soA[ks2 * 2 + r] = (arow0 + r * 128 + (tid >> 2)) * KD + ks2 * 32 + gsrc;
      soB[ks2 * 2 + r] = (r * 128 + (tid >> 2)) * KD + ks2 * 32 + gsrc;
    }
  const int ldst = w * 512;

#define STAGE_A(t, ks2, r) GLDS16((f16*)Ag + soA[(ks2)*2+(r)] + (t)*64, \
      la + ((t)&1)*16384 + (ks2)*8192 + (r)*4096 + ldst)
#define STAGE_B(t, ks2, r) GLDS16((f16*)Bg + soB[(ks2)*2+(r)] + (t)*64, \
      lb + ((t)&1)*16384 + (ks2)*8192 + (r)*4096 + ldst)

  const int raA = (wm * 128 + ln) * 32 + slotx;
  const int raB = (wn * 64 + ln) * 32 + slotx;

  STAGE_A(0, 0, 0); STAGE_A(0, 0, 1); STAGE_B(0, 0, 0); STAGE_B(0, 0, 1);
  STAGE_A(0, 1, 0); STAGE_A(0, 1, 1); STAGE_B(0, 1, 0); STAGE_B(0, 1, 1);
  asm volatile("s_waitcnt vmcnt(0)" ::: "memory");
  __builtin_amdgcn_s_barrier();

  half8 af[4], bf[4];

#pragma unroll 1
  for (int t = 0; t < 7; ++t) {
    const int cur = t & 1;
    const f16* lac = la + cur * 16384;
    const f16* lbc = lb + cur * 16384;
    load4(lbc + raB, bf);
    load4(lac + raA, af);
    STAGE_A(t + 1, 0, 0); STAGE_A(t + 1, 0, 1);
    BAR_MFMA_OPEN(); mfma16x<SW, 0>(acc, af, bf); MFMA_CLOSE();
    load4(lac + raA + 4 * 512, af);
    STAGE_B(t + 1, 0, 0); STAGE_B(t + 1, 0, 1);
    BAR_MFMA_OPEN(); mfma16x<SW, 4>(acc, af, bf); MFMA_CLOSE_GATE4();
    load4(lbc + 8192 + raB, bf);
    load4(lac + 8192 + raA, af);
    STAGE_A(t + 1, 1, 0); STAGE_A(t + 1, 1, 1);
    BAR_MFMA_OPEN(); mfma16x<SW, 0>(acc, af, bf); MFMA_CLOSE();
    load4(lac + 8192 + raA + 4 * 512, af);
    STAGE_B(t + 1, 1, 0); STAGE_B(t + 1, 1, 1);
    BAR_MFMA_OPEN(); mfma16x<SW, 4>(acc, af, bf); MFMA_CLOSE_GATE4();
  }
  {
    const f16* lac = la + 16384;
    const f16* lbc = lb + 16384;
    load4(lbc + raB, bf);
    load4(lac + raA, af);
    BAR_MFMA_OPEN(); mfma16x<SW, 0>(acc, af, bf); MFMA_CLOSE();
    load4(lac + raA + 4 * 512, af);
    BAR_MFMA_OPEN(); mfma16x<SW, 4>(acc, af, bf); MFMA_CLOSE_GATE0();
    load4(lbc + 8192 + raB, bf);
    load4(lac + 8192 + raA, af);
    BAR_MFMA_OPEN(); mfma16x<SW, 0>(acc, af, bf); MFMA_CLOSE();
    load4(lac + 8192 + raA + 4 * 512, af);
    __builtin_amdgcn_s_barrier();
    asm volatile("s_waitcnt lgkmcnt(0)" ::: "memory");
    __builtin_amdgcn_sched_barrier(0);
    mfma16x<SW, 4>(acc, af, bf);
  }
#undef STAGE_A
#undef STAGE_B
}

// ---------------- kernel 1a: Q,K projection (swapped orientation) ----------------
__global__ __launch_bounds__(512, 2) void k_qk256(
    const f16* __restrict__ A, const f16* __restrict__ wt,
    const float* __restrict__ bq, const float* __restrict__ bk,
    f16* __restrict__ qb, f16* __restrict__ kb) {
  __shared__ f16 smem[65536];
  const int nwg8 = 1024 / 8;
  const int f = (blockIdx.x & 7) * nwg8 + (blockIdx.x >> 3);
  const int ntile = f & 3, mtile = f >> 2;
  const int arow0 = mtile * 256;
  const f16* Bg = wt + ntile * 256 * KD;

  f32x4 acc[8][4] = {};
  gemm256_main<true>(A, Bg, arow0, smem, acc);

  const int tid = threadIdx.x;
  const int w = tid >> 6, lane = tid & 63;
  const int ln = lane & 15, g = lane >> 4;
  const int wm = w >> 2, wn = w & 3;
  const int cslab = (ntile & 1) << 8;
  const float* bias = (ntile < 2) ? bq : bk;
  f16* dst = (ntile < 2) ? qb : kb;
#pragma unroll
  for (int n = 0; n < 4; ++n) {
    const int cg = cslab + wn * 64 + n * 16 + g * 4;
    const f32x4 b4 = *(const f32x4*)(bias + cg);
    const int h = cg >> 6, d = cg & 63;
#pragma unroll
    for (int m = 0; m < 8; ++m) {
      const int tk = arow0 + wm * 128 + m * 16 + ln;
      const int b = tk >> 7, tr = tk & 127;
      half4 o;
#pragma unroll
      for (int r = 0; r < 4; ++r) o[r] = (f16)(acc[m][n][r] + b4[r]);
      *(half4*)(dst + ((b * NH + h) * NQ + tr) * DH + d) = o;
    }
  }
}

// ---------------- kernel 1b: V projection (normal orientation, V^T out) ----------------
__global__ __launch_bounds__(512, 2) void k_v256(
    const f16* __restrict__ A, const f16* __restrict__ wt,
    const float* __restrict__ bv, f16* __restrict__ vb) {
  __shared__ f16 smem[65536];
  const int nwg8 = 512 / 8;
  const int f = (blockIdx.x & 7) * nwg8 + (blockIdx.x >> 3);
  const int ntile = f & 1, mtile = f >> 1;
  const int arow0 = mtile * 256;
  const f16* Bg = wt + (1024 + ntile * 256) * KD;

  f32x4 acc[8][4] = {};
  gemm256_main<false>(A, Bg, arow0, smem, acc);

  const int tid = threadIdx.x;
  const int w = tid >> 6, lane = tid & 63;
  const int ln = lane & 15, g = lane >> 4;
  const int wm = w >> 2, wn = w & 3;
#pragma unroll
  for (int n = 0; n < 4; ++n) {
    const int cg = ntile * 256 + wn * 64 + n * 16 + ln;
    const float bias = bv[cg];
    const int h = cg >> 6, d = cg & 63;
#pragma unroll
    for (int m = 0; m < 8; ++m) {
      const int t0 = arow0 + wm * 128 + m * 16 + g * 4;
      const int b = t0 >> 7, tr = t0 & 127;
      half4 o;
#pragma unroll
      for (int r = 0; r < 4; ++r) o[r] = (f16)(acc[m][n][r] + bias);
      *(half4*)(vb + ((b * NH + h) * DH + d) * NQ + tr) = o;
    }
  }
}

// ======= kernel 2: fused causal attention + output projection, 1 block/batch =======
// 8 waves, 512 threads, 2 blocks/CU. Per head h: stage K_h [128][64]->klol (stride 72),
// V_h^T [64][128]->vl (stride 136); wave w owns q-rows 16w..16w+15; S via MFMA
// (A=Q-frag lane=q, B=K-frag lane=key); softmax unnormalized in-wave; P->plw (own-wave
// LDS, no barrier); PV (A=P, B=V^T-frag lane=d); O_h normalized -> klol (aliased after
// barrier); out-proj accumulates oacc += Wo_h^T-frag x O-frag (swapped: D[chan][tok]).
__global__ __launch_bounds__(512, 2) void k_fused(
    const f16* __restrict__ qbuf, const f16* __restrict__ kbuf,
    const f16* __restrict__ vbuf, const f16* __restrict__ wt,
    const float* __restrict__ bo, float* __restrict__ out) {
  __shared__ f16 klol[128 * 72];     // K_h staging, then O_h
  __shared__ f16 vl[64 * 136];       // V_h^T
  __shared__ f16 pl[8 * 16 * 132];   // per-wave P slices
  const int b = blockIdx.x;
  const int tid = threadIdx.x;
  const int w = tid >> 6, lane = tid & 63;
  const int ln = lane & 15, g = lane >> 4;
  const int wm = w >> 2, wn = w & 3;
  f16* plw = pl + w * (16 * 132);

  f32x4 oacc[4][8] = {};   // [mt: token quads][nt: chan tiles], D[chan=g*4+r][tok=ln]

#pragma unroll 1
  for (int h = 0; h < 8; ++h) {
    const f16* Kp = kbuf + (size_t)(b * NH + h) * (NQ * DH);
    const f16* Vp = vbuf + (size_t)(b * NH + h) * (DH * NQ);
    const f16* Qp = qbuf + (size_t)(b * NH + h) * (NQ * DH);
    // stage K (128x64) and V^T (64x128), 32 B/thread each
#pragma unroll
    for (int i = 0; i < 2; ++i) {
      const int e = i * 4096 + tid * 8;
      *(half8*)(klol + (e >> 6) * 72 + (e & 63)) = *(const half8*)(Kp + e);
    }
#pragma unroll
    for (int i = 0; i < 2; ++i) {
      const int e = i * 4096 + tid * 8;
      *(half8*)(vl + (e >> 7) * 136 + (e & 127)) = *(const half8*)(Vp + e);
    }
    half8 qf[2];
#pragma unroll
    for (int kf = 0; kf < 2; ++kf)
      qf[kf] = *(const half8*)(Qp + (w * 16 + ln) * DH + kf * 32 + g * 8);
    __syncthreads();

    // S = Q K^T for this wave's 16 q-rows (full 128 keys; masked tiles exp to 0)
    f32x4 s[8] = {};
#pragma unroll
    for (int kf = 0; kf < 2; ++kf)
#pragma unroll
      for (int n = 0; n < 8; ++n) {
        half8 kfr = *(const half8*)(klol + (n * 16 + ln) * 72 + kf * 32 + g * 8);
        s[n] = MFMA16(qf[kf], kfr, s[n]);
      }
    // softmax: q = 16w + g*4 + r, key = 16n + ln; mask BEFORE 1/sqrt(d) per reference
    float inv_[4];
#pragma unroll
    for (int r = 0; r < 4; ++r) {
      const int q = w * 16 + g * 4 + r;
      float z[8], rm = -1e30f;
#pragma unroll
      for (int n = 0; n < 8; ++n) {
        const int col = n * 16 + ln;
        z[n] = s[n][r] * 0.125f + ((col > q) ? -12500.0f : 0.0f);
        rm = fmaxf(rm, z[n]);
      }
      rm = fmaxf(rm, __shfl_xor(rm, 1));
      rm = fmaxf(rm, __shfl_xor(rm, 2));
      rm = fmaxf(rm, __shfl_xor(rm, 4));
      rm = fmaxf(rm, __shfl_xor(rm, 8));
      float rs = 0.f;
#pragma unroll
      for (int n = 0; n < 8; ++n) {
        const float p = __expf(z[n] - rm);   // masked cols -> exact 0
        rs += p;
        plw[(g * 4 + r) * 132 + n * 16 + ln] = (f16)p;
      }
      rs += __shfl_xor(rs, 1);
      rs += __shfl_xor(rs, 2);
      rs += __shfl_xor(rs, 4);
      rs += __shfl_xor(rs, 8);
      inv_[r] = 1.0f / rs;
    }
    // O = P V (own-wave P slice; compiler orders same-wave LDS RAW)
    f32x4 o[4] = {};
#pragma unroll
    for (int kf = 0; kf < 4; ++kf) {
      half8 pf = *(const half8*)(plw + ln * 132 + kf * 32 + g * 8);
#pragma unroll
      for (int n = 0; n < 4; ++n) {
        half8 vf = *(const half8*)(vl + (n * 16 + ln) * 136 + kf * 32 + g * 8);
        o[n] = MFMA16(pf, vf, o[n]);
      }
    }
    __syncthreads();   // all waves past kl reads -> reuse klol for O_h
#pragma unroll
    for (int n = 0; n < 4; ++n)
#pragma unroll
      for (int r = 0; r < 4; ++r)
        klol[(w * 16 + g * 4 + r) * 72 + n * 16 + ln] = (f16)(o[n][r] * inv_[r]);
    __syncthreads();
    // out-proj: oacc[chan][tok] += Wo_h^T x O_h   (B-reads from L2-resident wt)
    const f16* woh = wt + (size_t)(1536 + wn * 128) * KD + h * 64;
    half8 of[4][2];
#pragma unroll
    for (int mt = 0; mt < 4; ++mt)
#pragma unroll
      for (int kf = 0; kf < 2; ++kf)
        of[mt][kf] = *(const half8*)(klol + (wm * 64 + mt * 16 + ln) * 72 + kf * 32 + g * 8);
#pragma unroll
    for (int nt = 0; nt < 8; ++nt) {
      half8 wf0 = *(const half8*)(woh + (nt * 16 + ln) * KD + g * 8);
      half8 wf1 = *(const half8*)(woh + (nt * 16 + ln) * KD + 32 + g * 8);
#pragma unroll
      for (int mt = 0; mt < 4; ++mt) {
        oacc[mt][nt] = MFMA16(wf0, of[mt][0], oacc[mt][nt]);
        oacc[mt][nt] = MFMA16(wf1, of[mt][1], oacc[mt][nt]);
      }
    }
    __syncthreads();   // out-proj LDS reads done before next head's staging
  }
  // epilogue: contiguous f32x4 stores (4 chans per store)
#pragma unroll
  for (int nt = 0; nt < 8; ++nt) {
    const int chan = wn * 128 + nt * 16 + g * 4;
    const f32x4 b4 = *(const f32x4*)(bo + chan);
#pragma unroll
    for (int mt = 0; mt < 4; ++mt) {
      const int tok = b * NQ + wm * 64 + mt * 16 + ln;
      *(f32x4*)(out + (size_t)tok * CH + chan) = oacc[mt][nt] + b4;
    }
  }
}

extern "C" void kernel_launch(void* const* d_in, const int* in_sizes, int n_in,
                              void* d_out, int out_size, void* d_ws, size_t ws_size,
                              hipStream_t stream) {
  (void)in_sizes; (void)n_in; (void)out_size; (void)ws_size;
  const float* x  = (const float*)d_in[0];
  const float* Wq = (const float*)d_in[1];
  const float* bq = (const float*)d_in[2];
  const float* Wk = (const float*)d_in[3];
  const float* bk = (const float*)d_in[4];
  const float* Wv = (const float*)d_in[5];
  const float* bv = (const float*)d_in[6];
  const float* Wo = (const float*)d_in[7];
  const float* bo = (const float*)d_in[8];
  float* out = (float*)d_out;

  char* ws = (char*)d_ws;
  const size_t SZ = (size_t)MTOK * KD * sizeof(f16);  // 64 MB
  f16* xb = (f16*)(ws);
  f16* qb = (f16*)(ws + SZ);
  f16* kb = (f16*)(ws + 2 * SZ);
  f16* vb = (f16*)(ws + 3 * SZ);
  f16* wt = (f16*)(ws + 4 * SZ);

  k_cvt<<<2048, 256, 0, stream>>>(x, xb);
  k_wt<<<2048, 256, 0, stream>>>(Wq, Wk, Wv, Wo, wt);
  k_qk256<<<1024, 512, 0, stream>>>(xb, wt, bq, bk, qb, kb);
  k_v256<<<512, 512, 0, stream>>>(xb, wt, bv, vb);
  k_fused<<<512, 512, 0, stream>>>(qb, kb, vb, wt, bo, out);
}

// Round 4
// 309.506 us; speedup vs baseline: 1.2603x; 1.2603x over previous
//
#include <hip/hip_runtime.h>

typedef _Float16 f16;
typedef _Float16 half8 __attribute__((ext_vector_type(8)));
typedef _Float16 half4 __attribute__((ext_vector_type(4)));
typedef float f32x4 __attribute__((ext_vector_type(4)));

#define B_SZ 512
#define NQ   128
#define CH   512
#define NH   8
#define DH   64
#define MTOK (B_SZ*NQ)   // 65536 tokens
#define KD   512

#define MFMA16(a,b,c) __builtin_amdgcn_mfma_f32_16x16x32_f16((a),(b),(c),0,0,0)

// global -> LDS direct DMA, 16B per lane. LDS dest is wave-uniform base + lane*16.
#define GLDS16(g,l) __builtin_amdgcn_global_load_lds( \
    (__attribute__((address_space(1))) void*)(g), \
    (__attribute__((address_space(3))) void*)(l), 16, 0, 0)

// ---------------- kernel 0a: x fp32 -> fp16 ----------------
__global__ __launch_bounds__(256) void k_cvt(const float* __restrict__ x,
                                             f16* __restrict__ xb) {
  const int n8 = MTOK * KD / 8;
  int i = blockIdx.x * blockDim.x + threadIdx.x;
  const int stride = gridDim.x * blockDim.x;
  for (; i < n8; i += stride) {
    f32x4 a = ((const f32x4*)x)[2 * i];
    f32x4 b = ((const f32x4*)x)[2 * i + 1];
    half8 h;
    h[0] = (f16)a[0]; h[1] = (f16)a[1]; h[2] = (f16)a[2]; h[3] = (f16)a[3];
    h[4] = (f16)b[0]; h[5] = (f16)b[1]; h[6] = (f16)b[2]; h[7] = (f16)b[3];
    ((half8*)xb)[i] = h;
  }
}

// ---------------- kernel 0b: W^T fp32 -> fp16 (B^T layout) ----------------
// wt rows 0..511 = Wq cols, 512..1023 = Wk cols, 1024..1535 = Wv cols, 1536..2047 = Wo cols
__global__ __launch_bounds__(256) void k_wt(const float* __restrict__ Wq,
                                            const float* __restrict__ Wk,
                                            const float* __restrict__ Wv,
                                            const float* __restrict__ Wo,
                                            f16* __restrict__ wt) {
  const int n = blockIdx.x;
  const float* W = (n < 512) ? Wq : (n < 1024) ? Wk : (n < 1536) ? Wv : Wo;
  const int c = n & 511;
  for (int k = threadIdx.x; k < 512; k += blockDim.x)
    wt[n * 512 + k] = (f16)W[k * 512 + c];
}

// ---------------- kernel 1: fused QKV projection GEMM (128x128, BK=32) ----------------
// C[m][n] = sum_k A[m][k] * Bw[n][k];  M=65536, N=1536, K=512
// T2 swizzle on both LDS tiles: LDS[row][slot] holds global slot (slot ^ ((row>>1)&3)),
// slot = 8-f16 (16 B) chunk. Applied as pre-swizzled global SOURCE (linear GLDS dest)
// + swizzled ds_read. Eliminates the 8-way conflict of the [*][32] tile.
// XCD mapping: xcd = bid&7 owns mtiles [xcd*64, xcd*64+64); the 12 ntile-blocks of an
// mtile run on one XCD -> A panel fetched once into that XCD's L2.
__global__ __launch_bounds__(256, 4) void k_qkv(
    const f16* __restrict__ A, const f16* __restrict__ Bw,
    const float* __restrict__ bq, const float* __restrict__ bk,
    const float* __restrict__ bv,
    f16* __restrict__ qb, f16* __restrict__ kb, f16* __restrict__ vb) {
  __shared__ f16 la[128 * 32];
  __shared__ f16 lb[128 * 32];
  const int tid = threadIdx.x;
  const int w = tid >> 6, lane = tid & 63;
  const int ln = lane & 15, g = lane >> 4;
  const int wr = w >> 1, wc = w & 1;
  const int s = blockIdx.x >> 3;
  const int ml = s / 12;                       // uniform scalar div
  const int ntile = s - ml * 12;
  const int mtile = (blockIdx.x & 7) * 64 + ml;

  // staging: lane writes LDS slot (lane&3) of row w*16+(lane>>2); source slot pre-swizzled
  const int srow = w * 16 + (lane >> 2);
  const int scol = ((lane & 3) ^ ((lane >> 3) & 3)) * 8;
  const f16* gA = A + (mtile * 128 + srow) * KD + scol;
  const f16* gB = Bw + (ntile * 128 + srow) * KD + scol;
  f16* lA = la + w * 512;
  f16* lB = lb + w * 512;
  const int slotx = (g ^ ((ln >> 1) & 3)) * 8;   // swizzled read slot (lane-const)

  f32x4 acc[4][4] = {};

  for (int kt = 0; kt < 16; ++kt) {
    const int k0 = kt * 32;
    GLDS16(gA + k0, lA);
    GLDS16(gA + 64 * KD + k0, lA + 2048);
    GLDS16(gB + k0, lB);
    GLDS16(gB + 64 * KD + k0, lB + 2048);
    __syncthreads();   // compiler drains vmcnt before s_barrier
    half8 af[4], bf[4];
#pragma unroll
    for (int m = 0; m < 4; ++m)
      af[m] = *(const half8*)(la + (wr * 64 + m * 16 + ln) * 32 + slotx);
#pragma unroll
    for (int n = 0; n < 4; ++n)
      bf[n] = *(const half8*)(lb + (wc * 64 + n * 16 + ln) * 32 + slotx);
#pragma unroll
    for (int m = 0; m < 4; ++m)
#pragma unroll
      for (int n = 0; n < 4; ++n)
        acc[m][n] = MFMA16(af[m], bf[n], acc[m][n]);
    __syncthreads();
  }

  const int b = mtile;  // 128 rows per tile == one batch
  const int colbase = ntile * 128 + wc * 64;
#pragma unroll
  for (int m = 0; m < 4; ++m) {
    const int nn0 = wr * 64 + m * 16 + g * 4;  // token row in batch (reg 0)
#pragma unroll
    for (int n = 0; n < 4; ++n) {
      const int col = colbase + n * 16 + ln;
      const int which = col >> 9;      // 0=Q 1=K 2=V (uniform per n)
      const int c = col & 511;
      const int h = c >> 6, d = c & 63;
      const float bias = (which == 0) ? bq[c] : (which == 1) ? bk[c] : bv[c];
      if (which < 2) {
        f16* dst = ((which == 0) ? qb : kb) + ((b * NH + h) * NQ + nn0) * DH + d;
#pragma unroll
        for (int r = 0; r < 4; ++r)
          dst[r * DH] = (f16)(acc[m][n][r] + bias);
      } else {
        half4 v4;
#pragma unroll
        for (int r = 0; r < 4; ++r)
          v4[r] = (f16)(acc[m][n][r] + bias);
        *(half4*)(vb + ((b * NH + h) * DH + d) * NQ + nn0) = v4;  // V^T
      }
    }
  }
}

// ---------------- kernel 2: causal attention, one block per (b,h) ----------------
__global__ __launch_bounds__(256, 2) void k_attn(
    const f16* __restrict__ qbuf, const f16* __restrict__ kbuf,
    const f16* __restrict__ vbuf, f16* __restrict__ ao) {
  __shared__ f16 kl[128 * 72];   // K [key][d], padded stride 72
  __shared__ f16 vl[64 * 136];   // V^T [d][key], padded stride 136
  __shared__ f16 pl[128 * 136];  // P [q][key], padded stride 136
  const int bh = blockIdx.x;
  const f16* Qp = qbuf + bh * (NQ * DH);
  const f16* Kp = kbuf + bh * (NQ * DH);
  const f16* Vp = vbuf + bh * (DH * NQ);
  const int tid = threadIdx.x;
  const int w = tid >> 6, lane = tid & 63;
  const int ln = lane & 15, g = lane >> 4;

#pragma unroll
  for (int i = 0; i < 4; ++i) {
    const int e = i * 2048 + tid * 8;
    *(half8*)(kl + (e >> 6) * 72 + (e & 63)) = *(const half8*)(Kp + e);
  }
#pragma unroll
  for (int i = 0; i < 4; ++i) {
    const int e = i * 2048 + tid * 8;
    *(half8*)(vl + (e >> 7) * 136 + (e & 127)) = *(const half8*)(Vp + e);
  }
  half8 qf[2][2];
#pragma unroll
  for (int m = 0; m < 2; ++m)
#pragma unroll
    for (int ks = 0; ks < 2; ++ks)
      qf[m][ks] = *(const half8*)(Qp + (w * 32 + m * 16 + ln) * DH + ks * 32 + g * 8);
  __syncthreads();

  f32x4 s[2][8] = {};
#pragma unroll
  for (int ks = 0; ks < 2; ++ks)
#pragma unroll
    for (int n = 0; n < 8; ++n) {
      half8 kf = *(const half8*)(kl + (n * 16 + ln) * 72 + ks * 32 + g * 8);
      s[0][n] = MFMA16(qf[0][ks], kf, s[0][n]);
      s[1][n] = MFMA16(qf[1][ks], kf, s[1][n]);
    }

  float inv[2][4];
#pragma unroll
  for (int m = 0; m < 2; ++m) {
#pragma unroll
    for (int r = 0; r < 4; ++r) {
      const int q = w * 32 + m * 16 + g * 4 + r;
      float z[8];
      float rm = -1e30f;
#pragma unroll
      for (int n = 0; n < 8; ++n) {
        const int col = n * 16 + ln;
        float zz = s[m][n][r] * 0.125f + ((col > q) ? -12500.0f : 0.0f);
        z[n] = zz;
        rm = fmaxf(rm, zz);
      }
      rm = fmaxf(rm, __shfl_xor(rm, 1));
      rm = fmaxf(rm, __shfl_xor(rm, 2));
      rm = fmaxf(rm, __shfl_xor(rm, 4));
      rm = fmaxf(rm, __shfl_xor(rm, 8));
      float rs = 0.f;
#pragma unroll
      for (int n = 0; n < 8; ++n) {
        const float p = __expf(z[n] - rm);   // masked cols -> exact 0
        rs += p;
        pl[q * 136 + n * 16 + ln] = (f16)p;  // unnormalized P
      }
      rs += __shfl_xor(rs, 1);
      rs += __shfl_xor(rs, 2);
      rs += __shfl_xor(rs, 4);
      rs += __shfl_xor(rs, 8);
      inv[m][r] = 1.0f / rs;
    }
  }

  f32x4 o[2][4] = {};
#pragma unroll
  for (int ks = 0; ks < 4; ++ks) {
    half8 pf0 = *(const half8*)(pl + (w * 32 + ln) * 136 + ks * 32 + g * 8);
    half8 pf1 = *(const half8*)(pl + (w * 32 + 16 + ln) * 136 + ks * 32 + g * 8);
#pragma unroll
    for (int n = 0; n < 4; ++n) {
      half8 vf = *(const half8*)(vl + (n * 16 + ln) * 136 + ks * 32 + g * 8);
      o[0][n] = MFMA16(pf0, vf, o[0][n]);
      o[1][n] = MFMA16(pf1, vf, o[1][n]);
    }
  }

  const int b = bh >> 3, h = bh & 7;
  f16* dst = ao + (b * NQ) * CH + h * DH;
#pragma unroll
  for (int m = 0; m < 2; ++m)
#pragma unroll
    for (int n = 0; n < 4; ++n)
#pragma unroll
      for (int r = 0; r < 4; ++r) {
        const int q = w * 32 + m * 16 + g * 4 + r;
        dst[q * CH + n * 16 + ln] = (f16)(o[m][n][r] * inv[m][r]);
      }
}

// ---------------- kernel 3: output projection GEMM (128x128, swizzled) ----------------
__global__ __launch_bounds__(256, 4) void k_out(
    const f16* __restrict__ A, const f16* __restrict__ Bw,
    const float* __restrict__ bo, float* __restrict__ out) {
  __shared__ f16 la[128 * 32];
  __shared__ f16 lb[128 * 32];
  const int tid = threadIdx.x;
  const int w = tid >> 6, lane = tid & 63;
  const int ln = lane & 15, g = lane >> 4;
  const int wr = w >> 1, wc = w & 1;
  const int s = blockIdx.x >> 3;
  const int ml = s >> 2;
  const int ntile = s & 3;
  const int mtile = (blockIdx.x & 7) * 64 + ml;

  const int srow = w * 16 + (lane >> 2);
  const int scol = ((lane & 3) ^ ((lane >> 3) & 3)) * 8;
  const f16* gA = A + (mtile * 128 + srow) * KD + scol;
  const f16* gB = Bw + (ntile * 128 + srow) * KD + scol;
  f16* lA = la + w * 512;
  f16* lB = lb + w * 512;
  const int slotx = (g ^ ((ln >> 1) & 3)) * 8;

  f32x4 acc[4][4] = {};

  for (int kt = 0; kt < 16; ++kt) {
    const int k0 = kt * 32;
    GLDS16(gA + k0, lA);
    GLDS16(gA + 64 * KD + k0, lA + 2048);
    GLDS16(gB + k0, lB);
    GLDS16(gB + 64 * KD + k0, lB + 2048);
    __syncthreads();
    half8 af[4], bf[4];
#pragma unroll
    for (int m = 0; m < 4; ++m)
      af[m] = *(const half8*)(la + (wr * 64 + m * 16 + ln) * 32 + slotx);
#pragma unroll
    for (int n = 0; n < 4; ++n)
      bf[n] = *(const half8*)(lb + (wc * 64 + n * 16 + ln) * 32 + slotx);
#pragma unroll
    for (int m = 0; m < 4; ++m)
#pragma unroll
      for (int n = 0; n < 4; ++n)
        acc[m][n] = MFMA16(af[m], bf[n], acc[m][n]);
    __syncthreads();
  }

  const int colbase = ntile * 128 + wc * 64;
#pragma unroll
  for (int m = 0; m < 4; ++m) {
    const int tok0 = mtile * 128 + wr * 64 + m * 16 + g * 4;
#pragma unroll
    for (int n = 0; n < 4; ++n) {
      const int col = colbase + n * 16 + ln;
      const float bias = bo[col];
      float* dst = out + tok0 * CH + col;
#pragma unroll
      for (int r = 0; r < 4; ++r)
        dst[r * CH] = acc[m][n][r] + bias;
    }
  }
}

extern "C" void kernel_launch(void* const* d_in, const int* in_sizes, int n_in,
                              void* d_out, int out_size, void* d_ws, size_t ws_size,
                              hipStream_t stream) {
  (void)in_sizes; (void)n_in; (void)out_size; (void)ws_size;
  const float* x  = (const float*)d_in[0];
  const float* Wq = (const float*)d_in[1];
  const float* bq = (const float*)d_in[2];
  const float* Wk = (const float*)d_in[3];
  const float* bk = (const float*)d_in[4];
  const float* Wv = (const float*)d_in[5];
  const float* bv = (const float*)d_in[6];
  const float* Wo = (const float*)d_in[7];
  const float* bo = (const float*)d_in[8];
  float* out = (float*)d_out;

  char* ws = (char*)d_ws;
  const size_t SZ = (size_t)MTOK * KD * sizeof(f16);  // 64 MB
  f16* xb = (f16*)(ws);                // x in fp16
  f16* qb = (f16*)(ws + SZ);           // Q [b][h][n][d]
  f16* kb = (f16*)(ws + 2 * SZ);       // K [b][h][n][d]
  f16* vb = (f16*)(ws + 3 * SZ);       // V^T [b][h][d][n]
  f16* wt = (f16*)(ws + 4 * SZ);       // W^T fp16, 2048x512
  f16* ao = xb;                        // attn out aliases xb (xb dead by then)

  k_cvt<<<2048, 256, 0, stream>>>(x, xb);
  k_wt<<<2048, 256, 0, stream>>>(Wq, Wk, Wv, Wo, wt);
  k_qkv<<<6144, 256, 0, stream>>>(xb, wt, bq, bk, bv, qb, kb, vb);
  k_attn<<<4096, 256, 0, stream>>>(qb, kb, vb, ao);
  k_out<<<2048, 256, 0, stream>>>(ao, wt + 1536 * KD, bo, out);
}